// Round 10
// baseline (295.640 us; speedup 1.0000x reference)
//
#include <hip/hip_runtime.h>
#include <hip/hip_bf16.h>
#include <stdint.h>

// B=8, S=1024, NX=1024, H=16, D=64
typedef __bf16 bf16x8 __attribute__((ext_vector_type(8)));
typedef float  f32x4  __attribute__((ext_vector_type(4)));
typedef float  f32x16 __attribute__((ext_vector_type(16)));

#define BARRIER() asm volatile("s_barrier" ::: "memory")
#define VMCNT(n)  asm volatile("s_waitcnt vmcnt(" #n ")" ::: "memory")
#define LGKM0()   asm volatile("s_waitcnt lgkmcnt(0)" ::: "memory")
#define SCHED0()  __builtin_amdgcn_sched_barrier(0)

__device__ __forceinline__ void gload_lds16(const void* g, void* l) {
  __builtin_amdgcn_global_load_lds(
      (const __attribute__((address_space(1))) unsigned int*)g,
      (__attribute__((address_space(3))) unsigned int*)l, 16, 0, 0);
}

// ---------------- cast fp32 -> bf16, 4 elems/thread ----------------
__global__ void k_cast(const float* __restrict__ in, __bf16* __restrict__ out, int n4) {
  int i = blockIdx.x * blockDim.x + threadIdx.x;
  if (i >= n4) return;
  float4 v = reinterpret_cast<const float4*>(in)[i];
  union { __bf16 h[4]; uint64_t u; } c;
  c.h[0] = (__bf16)v.x; c.h[1] = (__bf16)v.y; c.h[2] = (__bf16)v.z; c.h[3] = (__bf16)v.w;
  *reinterpret_cast<uint64_t*>(out + 4l * i) = c.u;
}

// ------------- transpose fp32 [R][C] -> bf16 [C][R] ----------------
__global__ void k_transpose_cast(const float* __restrict__ in, __bf16* __restrict__ out,
                                 int R, int C) {
  __shared__ float t[32][33];
  const int tx = threadIdx.x & 31, ty = threadIdx.x >> 5;  // 32 x 8
  const int c0 = blockIdx.x * 32, r0 = blockIdx.y * 32;
#pragma unroll
  for (int rr = 0; rr < 4; ++rr)
    t[ty * 4 + rr][tx] = in[(long)(r0 + ty * 4 + rr) * C + c0 + tx];
  __syncthreads();
#pragma unroll
  for (int rr = 0; rr < 4; ++rr)
    out[(long)(c0 + ty * 4 + rr) * R + r0 + tx] = (__bf16)t[tx][ty * 4 + rr];
}

// ============ GEMM: C = A[M,K] * Bt[N,K]^T + bias ============
// Tile 256x128, BK=32, 4 waves (2m x 2n), PER-WAVE OUTPUT 128x64 (acc[8][4]).
// Arithmetic intensity: 42.7 FLOP per LDS-byte (2x the old 64x64/wave scheme,
// which was LDS-read-bandwidth-bound at ~23% MfmaUtil -- R2..R8 postmortem).
// LDS: 2 buf x {A 256x32 (16K) + B 128x32 (8K)} = 48 KB -> 2 blocks/CU.
// Per K-step: stage next tile (6 gloads), VMCNT(6) counted, 2 barriers,
// 12 ds_read_b128, 32 MFMA.  Swizzle: byte-col ^= ((row&3)<<4) (64B rows).
// MODE 0: scatter -> q[B,H,S,D] (pre-scaled 1/8), k[B,H,S,D], v^T[B,H,D,S]
// MODE 1: fp32 -> fo[M,N]
template <int MODE>
__launch_bounds__(256, 2)
__global__ void k_gemm3(const __bf16* __restrict__ A, const __bf16* __restrict__ Bt,
                        const float* __restrict__ bias, int M, int N, int K, int NBX,
                        __bf16* __restrict__ qo, __bf16* __restrict__ ko,
                        __bf16* __restrict__ vo, float* __restrict__ fo) {
  __shared__ __bf16 lds[2][12288];  // [buf][A: 0..8192 | B: 8192..12288]
  const int tid = threadIdx.x;
  const int l = tid & 63, w = tid >> 6;          // 4 waves
  const int lm = l & 15, lq = l >> 4;
  const int wm = w >> 1, wn = w & 1;
  // XCD-affinity: xcd owns bn in [xcd*NBX, (xcd+1)*NBX)
  const int xcd = blockIdx.x & 7, s = blockIdx.x >> 3;
  const int bn = xcd * NBX + s % NBX;
  const int bm = s / NBX;
  const int nt = K >> 5;

  // staging: thread covers row (li*64 + tid>>2), 16B chunk (tid&3), pre-swizzled src
  const int rA = tid >> 2;                                     // 0..63
  const int scol = (((tid & 3) * 16) ^ ((rA & 3) << 4)) >> 1;  // elements (swizzled)
  long a_off[4], b_off[2];
#pragma unroll
  for (int li = 0; li < 4; ++li)
    a_off[li] = (long)(bm * 256 + li * 64 + rA) * K + scol;
#pragma unroll
  for (int li = 0; li < 2; ++li)
    b_off[li] = (long)(bn * 128 + li * 64 + rA) * K + scol;

#define STAGE(buf, t) { \
    gload_lds16(A + a_off[0] + (long)(t) * 32, &lds[buf][tid * 8]); \
    gload_lds16(A + a_off[1] + (long)(t) * 32, &lds[buf][2048 + tid * 8]); \
    gload_lds16(A + a_off[2] + (long)(t) * 32, &lds[buf][4096 + tid * 8]); \
    gload_lds16(A + a_off[3] + (long)(t) * 32, &lds[buf][6144 + tid * 8]); \
    gload_lds16(Bt + b_off[0] + (long)(t) * 32, &lds[buf][8192 + tid * 8]); \
    gload_lds16(Bt + b_off[1] + (long)(t) * 32, &lds[buf][10240 + tid * 8]); }

  // fragment read offsets (element units; row stride 32 elems = 64 B)
  const int cofs = ((lq * 16) ^ ((lm & 3) << 4)) >> 1;
  const int arow = wm * 128 + lm;   // + mi*16
  const int brow = wn * 64 + lm;    // + ni*16

  f32x4 acc[8][4] = {};

  STAGE(0, 0);  // prologue: tile 0 in flight (6 loads)

  for (int t = 0; t < nt; ++t) {
    const int cur = t & 1;
    if (t + 1 < nt) { STAGE(cur ^ 1, t + 1); VMCNT(6); }
    else VMCNT(0);
    BARRIER();
    const __bf16* Lb = lds[cur];
    bf16x8 af[8], bfr[4];
#pragma unroll
    for (int mi = 0; mi < 8; ++mi)
      af[mi] = *(const bf16x8*)&Lb[(arow + mi * 16) * 32 + cofs];
#pragma unroll
    for (int ni = 0; ni < 4; ++ni)
      bfr[ni] = *(const bf16x8*)&Lb[8192 + (brow + ni * 16) * 32 + cofs];
    LGKM0(); SCHED0();
    __builtin_amdgcn_s_setprio(1);
#pragma unroll
    for (int mi = 0; mi < 8; ++mi)
#pragma unroll
      for (int ni = 0; ni < 4; ++ni)
        acc[mi][ni] = __builtin_amdgcn_mfma_f32_16x16x32_bf16(af[mi], bfr[ni],
                                                              acc[mi][ni], 0, 0, 0);
    __builtin_amdgcn_s_setprio(0);
    SCHED0();
    BARRIER();  // reads done before next iter's STAGE overwrites buf^1
  }

  if (MODE == 0) {
#pragma unroll
    for (int ni = 0; ni < 4; ++ni) {
      const int c = bn * 128 + wn * 64 + ni * 16 + lm;
      const float bv = bias[c];
      const int which = c >> 10, cc = c & 1023, hh = cc >> 6, d = cc & 63;
#pragma unroll
      for (int mi = 0; mi < 8; ++mi)
#pragma unroll
        for (int i = 0; i < 4; ++i) {
          const int r = bm * 256 + wm * 128 + mi * 16 + lq * 4 + i;
          const int b = r >> 10, s_ = r & 1023;
          float fv = acc[mi][ni][i] + bv;
          if (which == 0) fv *= 0.125f;  // fold 1/sqrt(D) into Q
          const __bf16 v = (__bf16)fv;
          const long hb = (long)(b * 16 + hh);
          if (which == 0)      qo[(hb * 1024 + s_) * 64 + d] = v;
          else if (which == 1) ko[(hb * 1024 + s_) * 64 + d] = v;
          else                 vo[(hb * 64 + d) * 1024 + s_] = v;
        }
    }
  } else {
#pragma unroll
    for (int ni = 0; ni < 4; ++ni) {
      const int c = bn * 128 + wn * 64 + ni * 16 + lm;
      const float bv = bias[c];
#pragma unroll
      for (int mi = 0; mi < 8; ++mi)
#pragma unroll
        for (int i = 0; i < 4; ++i) {
          const int r = bm * 256 + wm * 128 + mi * 16 + lq * 4 + i;
          fo[(long)r * N + c] = acc[mi][ni][i] + bv;
        }
    }
  }
#undef STAGE
}

// -------- causal flash attention, KVBLK=64, swapped-QK^T, no LDS --------
__device__ __forceinline__ void attn_qtile(const __bf16* __restrict__ Q,
                                           const __bf16* __restrict__ Kh,
                                           const __bf16* __restrict__ Vt,
                                           __bf16* __restrict__ ob,
                                           int b, int h, int qbw, int l) {
  const int lm = l & 31, hi = l >> 5;

  bf16x8 qf[4];
#pragma unroll
  for (int ds = 0; ds < 4; ++ds)
    qf[ds] = *(const bf16x8*)(Q + (long)(qbw + lm) * 64 + ds * 16 + hi * 8);

  f32x16 oacc0 = {}, oacc1 = {};
  float m = -__builtin_inff(), s = 0.f;

  const int nt64 = (qbw >> 6) + 1;  // 64-key blocks; last may be part-masked
  for (int kt = 0; kt < nt64; ++kt) {
    const int k0 = kt * 64;
    f32x16 st0 = {}, st1 = {};
#pragma unroll
    for (int ds = 0; ds < 4; ++ds) {
      bf16x8 kf0 = *(const bf16x8*)(Kh + (long)(k0 + lm) * 64 + ds * 16 + hi * 8);
      bf16x8 kf1 = *(const bf16x8*)(Kh + (long)(k0 + 32 + lm) * 64 + ds * 16 + hi * 8);
      st0 = __builtin_amdgcn_mfma_f32_32x32x16_bf16(kf0, qf[ds], st0, 0, 0, 0);
      st1 = __builtin_amdgcn_mfma_f32_32x32x16_bf16(kf1, qf[ds], st1, 0, 0, 0);
    }
    if (kt == nt64 - 1) {  // diagonal / tail masking
      const int q = qbw + lm;
#pragma unroll
      for (int r = 0; r < 16; ++r) {
        const int key = k0 + (r & 3) + 8 * (r >> 2) + 4 * hi;
        if (key > q)      st0[r] = -__builtin_inff();
        if (key + 32 > q) st1[r] = -__builtin_inff();
      }
    }
    float tm = fmaxf(st0[0], st1[0]);
#pragma unroll
    for (int r = 1; r < 16; ++r) tm = fmaxf(tm, fmaxf(st0[r], st1[r]));
    tm = fmaxf(tm, __shfl_xor(tm, 32));
    if (!__all(tm <= m + 8.f)) {   // defer-max
      const float mn = fmaxf(m, tm);
      const float fac = __expf(m - mn);
      m = mn;
      s *= fac;
#pragma unroll
      for (int r = 0; r < 16; ++r) {
        const int qr = (r & 3) + 8 * (r >> 2) + 4 * hi;
        const float fr = __int_as_float(
            __builtin_amdgcn_ds_bpermute(qr * 4, __float_as_int(fac)));
        oacc0[r] *= fr; oacc1[r] *= fr;
      }
    }
    float ts = 0.f;
    unsigned int w8a[8], w8b[8];
#pragma unroll
    for (int t = 0; t < 8; ++t) {
      const float pa_ = __expf(st0[2 * t] - m), pb_ = __expf(st0[2 * t + 1] - m);
      ts += pa_ + pb_;
      union { __bf16 hh[2]; unsigned int u; } pk;
      pk.hh[0] = (__bf16)pa_; pk.hh[1] = (__bf16)pb_;
      w8a[t] = pk.u;
    }
#pragma unroll
    for (int t = 0; t < 8; ++t) {
      const float pa_ = __expf(st1[2 * t] - m), pb_ = __expf(st1[2 * t + 1] - m);
      ts += pa_ + pb_;
      union { __bf16 hh[2]; unsigned int u; } pk;
      pk.hh[0] = (__bf16)pa_; pk.hh[1] = (__bf16)pb_;
      w8b[t] = pk.u;
    }
    ts += __shfl_xor(ts, 32);
    s += ts;
    // build 4 PV A-frags: pa0/pa1 from w8a (keys k0+0..31), pa2/pa3 from w8b
    union { unsigned int wd[4]; bf16x8 v; } pa[4];
    {
      const unsigned int e0 = __shfl_xor(hi ? w8a[0] : w8a[2], 32);
      const unsigned int e1 = __shfl_xor(hi ? w8a[1] : w8a[3], 32);
      const unsigned int e2 = __shfl_xor(hi ? w8a[4] : w8a[6], 32);
      const unsigned int e3 = __shfl_xor(hi ? w8a[5] : w8a[7], 32);
      if (hi) {
        pa[0].wd[0] = e0;     pa[0].wd[1] = e1;     pa[0].wd[2] = w8a[2]; pa[0].wd[3] = w8a[3];
        pa[1].wd[0] = e2;     pa[1].wd[1] = e3;     pa[1].wd[2] = w8a[6]; pa[1].wd[3] = w8a[7];
      } else {
        pa[0].wd[0] = w8a[0]; pa[0].wd[1] = w8a[1]; pa[0].wd[2] = e0;     pa[0].wd[3] = e1;
        pa[1].wd[0] = w8a[4]; pa[1].wd[1] = w8a[5]; pa[1].wd[2] = e2;     pa[1].wd[3] = e3;
      }
    }
    {
      const unsigned int e0 = __shfl_xor(hi ? w8b[0] : w8b[2], 32);
      const unsigned int e1 = __shfl_xor(hi ? w8b[1] : w8b[3], 32);
      const unsigned int e2 = __shfl_xor(hi ? w8b[4] : w8b[6], 32);
      const unsigned int e3 = __shfl_xor(hi ? w8b[5] : w8b[7], 32);
      if (hi) {
        pa[2].wd[0] = e0;     pa[2].wd[1] = e1;     pa[2].wd[2] = w8b[2]; pa[2].wd[3] = w8b[3];
        pa[3].wd[0] = e2;     pa[3].wd[1] = e3;     pa[3].wd[2] = w8b[6]; pa[3].wd[3] = w8b[7];
      } else {
        pa[2].wd[0] = w8b[0]; pa[2].wd[1] = w8b[1]; pa[2].wd[2] = e0;     pa[2].wd[3] = e1;
        pa[3].wd[0] = w8b[4]; pa[3].wd[1] = w8b[5]; pa[3].wd[2] = e2;     pa[3].wd[3] = e3;
      }
    }
#pragma unroll
    for (int t = 0; t < 4; ++t) {
      bf16x8 vf0 = *(const bf16x8*)(Vt + (long)lm * 1024 + k0 + t * 16 + hi * 8);
      bf16x8 vf1 = *(const bf16x8*)(Vt + (long)(32 + lm) * 1024 + k0 + t * 16 + hi * 8);
      oacc0 = __builtin_amdgcn_mfma_f32_32x32x16_bf16(pa[t].v, vf0, oacc0, 0, 0, 0);
      oacc1 = __builtin_amdgcn_mfma_f32_32x32x16_bf16(pa[t].v, vf1, oacc1, 0, 0, 0);
    }
  }
  const float invs = 1.f / s;
#pragma unroll
  for (int r = 0; r < 16; ++r) {
    const int qr = (r & 3) + 8 * (r >> 2) + 4 * hi;
    const float inv = __int_as_float(
        __builtin_amdgcn_ds_bpermute(qr * 4, __float_as_int(invs)));
    const long row = (long)(b * 1024 + qbw + qr) * 1024 + h * 64;
    ob[row + lm]      = (__bf16)(oacc0[r] * inv);
    ob[row + 32 + lm] = (__bf16)(oacc1[r] * inv);
  }
}

// 512 blocks, XCD-affinity: the 4 blocks of one (b,h) land on one XCD.
__global__ __launch_bounds__(256, 2)
void k_attn(const __bf16* __restrict__ qb_, const __bf16* __restrict__ kb,
            const __bf16* __restrict__ vtb, __bf16* __restrict__ ob) {
  const int l = threadIdx.x & 63, w = threadIdx.x >> 6;
  const int bid = blockIdx.x;
  const int xcd = bid & 7, slot = bid >> 3;
  const int bh = xcd + 8 * (slot >> 2);
  const int j = slot & 3;
  const int wi = j * 4 + w;                      // 0..15
  const int b = bh >> 4, h = bh & 15;
  const __bf16* Q  = qb_ + (long)bh * 65536;
  const __bf16* Kh = kb  + (long)bh * 65536;
  const __bf16* Vt = vtb + (long)bh * 65536;
  attn_qtile(Q, Kh, Vt, ob, b, h, wi * 32, l);
  attn_qtile(Q, Kh, Vt, ob, b, h, (31 - wi) * 32, l);
}

extern "C" void kernel_launch(void* const* d_in, const int* in_sizes, int n_in,
                              void* d_out, int out_size, void* d_ws, size_t ws_size,
                              hipStream_t stream) {
  const float* x      = (const float*)d_in[0];
  const float* w_attn = (const float*)d_in[1];
  const float* b_attn = (const float*)d_in[2];
  const float* w_proj = (const float*)d_in[3];
  const float* b_proj = (const float*)d_in[4];
  float* out = (float*)d_out;

  char* ws = (char*)d_ws;
  const size_t SZ_XBF = (size_t)8192 * 1024 * 2;   // 16.8 MB
  __bf16* x_bf = (__bf16*)ws;  ws += SZ_XBF;
  __bf16* wat  = (__bf16*)ws;  ws += (size_t)3072 * 1024 * 2;
  __bf16* wpt  = (__bf16*)ws;  ws += (size_t)1024 * 1024 * 2;
  __bf16* qb   = (__bf16*)ws;  ws += SZ_XBF;       // [B,H,S,D], pre-scaled 1/8
  __bf16* kb   = (__bf16*)ws;  ws += SZ_XBF;       // [B,H,S,D]
  __bf16* vtb  = (__bf16*)ws;  ws += SZ_XBF;       // [B,H,D,S]
  __bf16* obf  = (__bf16*)ws;  ws += SZ_XBF;       // [B,S,NX]

  k_cast<<<8192, 256, 0, stream>>>(x, x_bf, 2097152);
  k_transpose_cast<<<dim3(96, 32), 256, 0, stream>>>(w_attn, wat, 1024, 3072);
  k_transpose_cast<<<dim3(32, 32), 256, 0, stream>>>(w_proj, wpt, 1024, 1024);
  // QKV: M=8192 (32 bm of 256) x N=3072 (24 bn of 128) -> 768 blocks; NBX=3
  k_gemm3<0><<<768, 256, 0, stream>>>(x_bf, wat, b_attn, 8192, 3072, 1024, 3,
                                      qb, kb, vtb, nullptr);
  k_attn<<<512, 256, 0, stream>>>(qb, kb, vtb, obf);
  // proj: 32 bm x 8 bn -> 256 blocks; NBX = 1
  k_gemm3<1><<<256, 256, 0, stream>>>(obf, wpt, b_proj, 8192, 1024, 1024, 1,
                                      nullptr, nullptr, nullptr, out);
}